// Round 4
// baseline (298.478 us; speedup 1.0000x reference)
//
#include <hip/hip_runtime.h>
#include <math.h>

#define PB    128
#define PHW   256
#define IMG_H 1024
#define IMG_W 1024
#define NBOX  16
#define NB    8
#define EPSF  1e-12f

// ---------------- kernel 1: antialiased bilinear downsample 256 -> 128 ----------------
__global__ void k_downsample(const float* __restrict__ patch, float* __restrict__ small) {
    int t = blockIdx.x * blockDim.x + threadIdx.x;
    if (t >= PB * PB * 3) return;
    int c    = t % 3;
    int rest = t / 3;
    int jl   = rest % PB;
    int il   = rest / PB;
    // sample points (antialias: kernel scale = 2)
    float sy = 2.f * il + 0.5f;
    float sx = 2.f * jl + 0.5f;
    float wy[4], wx[4];
    int   iy[4], ix[4];
    int ny = 0, nx = 0;
    float wys = 0.f, wxs = 0.f;
    #pragma unroll
    for (int d = -1; d <= 2; ++d) {
        int y = 2 * il + d;
        if (y >= 0 && y < PHW) {
            float w = 1.f - 0.5f * fabsf(sy - (float)y);
            iy[ny] = y; wy[ny] = w; wys += w; ++ny;
        }
        int x = 2 * jl + d;
        if (x >= 0 && x < PHW) {
            float w = 1.f - 0.5f * fabsf(sx - (float)x);
            ix[nx] = x; wx[nx] = w; wxs += w; ++nx;
        }
    }
    float acc = 0.f;
    for (int a = 0; a < ny; ++a) {
        float rowa = 0.f;
        for (int b2 = 0; b2 < nx; ++b2)
            rowa += wx[b2] * patch[(iy[a] * PHW + ix[b2]) * 3 + c];
        acc += wy[a] * rowa;
    }
    small[t] = acc / (wys * wxs);
}

// ---------------- kernel 2: images + pasted tiles (last box wins) ----------------
__global__ void k_patched(const float* __restrict__ images, const float* __restrict__ small,
                          const int* __restrict__ box_yx, const int* __restrict__ dec,
                          float* __restrict__ out) {
    int b   = blockIdx.y;
    int tid = threadIdx.x;
    __shared__ int sby[NBOX], sbx[NBOX], sd0[NBOX], sd1[NBOX], sd2[NBOX];
    if (tid < NBOX) {
        sby[tid] = box_yx[(b * NBOX + tid) * 2 + 0];
        sbx[tid] = box_yx[(b * NBOX + tid) * 2 + 1];
        sd0[tid] = dec[(b * NBOX + tid) * 3 + 0];
        sd1[tid] = dec[(b * NBOX + tid) * 3 + 1];
        sd2[tid] = dec[(b * NBOX + tid) * 3 + 2];
    }
    __syncthreads();
    size_t imgbase = (size_t)b * (IMG_H * IMG_W * 3);
    const float4* in4  = (const float4*)(images + imgbase);
    float4*       out4 = (float4*)(out + imgbase);
    int q = blockIdx.x * blockDim.x + tid;          // float4 index within image
    float4 v = in4[q];
    float vv[4] = {v.x, v.y, v.z, v.w};
    int e0 = q * 4;
    #pragma unroll
    for (int k = 0; k < 4; ++k) {
        int e   = e0 + k;
        int y   = e / (IMG_W * 3);
        int rem = e - y * (IMG_W * 3);
        int x   = rem / 3;
        int c   = rem - x * 3;
        for (int n = NBOX - 1; n >= 0; --n) {
            int py = y - sby[n], px = x - sbx[n];
            if ((unsigned)py < (unsigned)PB && (unsigned)px < (unsigned)PB) {
                int i = py, j = px;
                if (sd2[n] > 0) i = PB - 1 - i;     // undo flip_up_down
                if (sd1[n] > 0) j = PB - 1 - j;     // undo flip_left_right
                int si, sj;
                if (sd0[n] > 0) { si = j; sj = PB - 1 - i; }  // undo rot90 k=1
                else            { si = i; sj = j; }
                vv[k] = small[(si * PB + sj) * 3 + c];
                break;
            }
        }
    }
    out4[q] = make_float4(vv[0], vv[1], vv[2], vv[3]);
}

// ---------------- kernel 3: sum of inverse-transformed gathered grad tiles ----------------
__global__ void k_sgrad(const float* __restrict__ gradients, const int* __restrict__ box_yx,
                        const int* __restrict__ dec, float* __restrict__ s_part, int ngroups) {
    int g = blockIdx.y;
    int t = blockIdx.x * blockDim.x + threadIdx.x;      // 0 .. 49151
    if (t >= PB * PB * 3) return;
    int c    = t % 3;
    int rest = t / 3;
    int j    = rest % PB;
    int i    = rest / PB;
    int boxes_per = (NB * NBOX) / ngroups;
    float acc = 0.f;
    for (int m = 0; m < boxes_per; ++m) {
        int box = g * boxes_per + m;                    // flat index b*16+n (scan order)
        int b   = box >> 4;
        int by = box_yx[box * 2 + 0];
        int bx = box_yx[box * 2 + 1];
        int d0 = dec[box * 3 + 0];
        int d1 = dec[box * 3 + 1];
        int d2 = dec[box * 3 + 2];
        int ii = i, jj = j;
        if (d0 > 0) { int ti = PB - 1 - jj; int tj = ii; ii = ti; jj = tj; } // rot90 k=3 eval
        if (d1 > 0) jj = PB - 1 - jj;
        if (d2 > 0) ii = PB - 1 - ii;
        const float* gb = gradients + (size_t)b * (IMG_H * IMG_W * 3);
        acc += gb[((by + ii) * IMG_W + (bx + jj)) * 3 + c];
    }
    s_part[(size_t)g * (PB * PB * 3) + t] = acc;
}

// ---------------- kernel 4: reduce group partials ----------------
__global__ void k_reduce(const float* __restrict__ s_part, float* __restrict__ S, int ngroups) {
    int t = blockIdx.x * blockDim.x + threadIdx.x;
    if (t >= PB * PB * 3) return;
    float a = 0.f;
    for (int g = 0; g < ngroups; ++g) a += s_part[(size_t)g * (PB * PB * 3) + t];
    S[t] = a;
}

// ---------------- kernel 5: upsample 128->256 + TV-loss gradient ----------------
__global__ void k_final(const float* __restrict__ S, const float* __restrict__ patch,
                        float* __restrict__ agg) {
    int t = blockIdx.x * blockDim.x + threadIdx.x;
    if (t >= PHW * PHW * 3) return;
    int c    = t % 3;
    int rest = t / 3;
    int v    = rest % PHW;
    int u    = rest / PHW;

    // ---- bilinear upsample of S ----
    float fy = 0.5f * u - 0.25f;
    float fx = 0.5f * v - 0.25f;
    int i0 = (int)floorf(fy);
    int j0 = (int)floorf(fx);
    float wy[2], wx[2];
    int   iy[2], jx[2];
    int ny = 0, nx = 0;
    float wys = 0.f, wxs = 0.f;
    #pragma unroll
    for (int d = 0; d < 2; ++d) {
        int i = i0 + d;
        if (i >= 0 && i < PB) {
            float w = 1.f - fabsf(fy - (float)i);
            iy[ny] = i; wy[ny] = w; wys += w; ++ny;
        }
        int jj = j0 + d;
        if (jj >= 0 && jj < PB) {
            float w = 1.f - fabsf(fx - (float)jj);
            jx[nx] = jj; wx[nx] = w; wxs += w; ++nx;
        }
    }
    float acc = 0.f;
    for (int a = 0; a < ny; ++a)
        for (int b2 = 0; b2 < nx; ++b2)
            acc += wy[a] * wx[b2] * S[(iy[a] * PB + jx[b2]) * 3 + c];
    acc /= (wys * wxs);

    // ---- TV-loss gradient (closed form) ----
    #define PAT(a, b) patch[((a) * PHW + (b)) * 3 + c]
    float p  = PAT(u, v);
    float dx = (v < PHW - 1) ? (p - PAT(u, v + 1)) : 0.f;
    float dy = (u < PHW - 1) ? (p - PAT(u + 1, v)) : 0.f;
    float r  = sqrtf(dx * dx + dy * dy + EPSF);
    float gsum = (dx + dy) / r;
    if (v > 0) {
        float pl  = PAT(u, v - 1);
        float dxl = pl - p;
        float dyl = (u < PHW - 1) ? (pl - PAT(u + 1, v - 1)) : 0.f;
        gsum -= dxl / sqrtf(dxl * dxl + dyl * dyl + EPSF);
    }
    if (u > 0) {
        float pu_ = PAT(u - 1, v);
        float dyu = pu_ - p;
        float dxu = (v < PHW - 1) ? (pu_ - PAT(u - 1, v + 1)) : 0.f;
        gsum -= dyu / sqrtf(dxu * dxu + dyu * dyu + EPSF);
    }
    #undef PAT
    agg[t] = acc + 0.5f * gsum;
}

extern "C" void kernel_launch(void* const* d_in, const int* in_sizes, int n_in,
                              void* d_out, int out_size, void* d_ws, size_t ws_size,
                              hipStream_t stream) {
    const float* images    = (const float*)d_in[0];
    const float* gradients = (const float*)d_in[1];
    const float* patch     = (const float*)d_in[2];
    const int*   box_yx    = (const int*)d_in[3];
    const int*   dec       = (const int*)d_in[4];

    float* out     = (float*)d_out;
    float* agg_out = out + (size_t)NB * IMG_H * IMG_W * 3;

    const size_t TILE = PB * PB * 3;   // 49152 floats
    int ngroups = 8;
    size_t need = TILE * (size_t)(1 + 8 + 1) * sizeof(float);   // small + parts + S
    if (ws_size < need) ngroups = 1;

    float* small  = (float*)d_ws;
    float* s_part = small + TILE;
    float* S      = s_part + (size_t)ngroups * TILE;

    hipLaunchKernelGGL(k_downsample, dim3(192), dim3(256), 0, stream, patch, small);
    hipLaunchKernelGGL(k_sgrad, dim3(192, ngroups), dim3(256), 0, stream,
                       gradients, box_yx, dec, s_part, ngroups);
    hipLaunchKernelGGL(k_reduce, dim3(192), dim3(256), 0, stream, s_part, S, ngroups);
    hipLaunchKernelGGL(k_patched, dim3((IMG_H * IMG_W * 3) / 4 / 256, NB), dim3(256), 0, stream,
                       images, small, box_yx, dec, out);
    hipLaunchKernelGGL(k_final, dim3((PHW * PHW * 3) / 256), dim3(256), 0, stream,
                       S, patch, agg_out);
}

// Round 5
// 283.302 us; speedup vs baseline: 1.0536x; 1.0536x over previous
//
#include <hip/hip_runtime.h>
#include <math.h>

#define PB    128
#define PHW   256
#define IMG_H 1024
#define IMG_W 1024
#define NBOX  16
#define NB    8
#define EPSF  1e-12f

// ---------------- kernel 1: antialiased bilinear downsample 256 -> 128 ----------------
__global__ void k_downsample(const float* __restrict__ patch, float* __restrict__ small) {
    int t = blockIdx.x * blockDim.x + threadIdx.x;
    if (t >= PB * PB * 3) return;
    int c    = t % 3;
    int rest = t / 3;
    int jl   = rest % PB;
    int il   = rest / PB;
    float sy = 2.f * il + 0.5f;
    float sx = 2.f * jl + 0.5f;
    float wy[4], wx[4];
    int   iy[4], ix[4];
    int ny = 0, nx = 0;
    float wys = 0.f, wxs = 0.f;
    #pragma unroll
    for (int d = -1; d <= 2; ++d) {
        int y = 2 * il + d;
        if (y >= 0 && y < PHW) {
            float w = 1.f - 0.5f * fabsf(sy - (float)y);
            iy[ny] = y; wy[ny] = w; wys += w; ++ny;
        }
        int x = 2 * jl + d;
        if (x >= 0 && x < PHW) {
            float w = 1.f - 0.5f * fabsf(sx - (float)x);
            ix[nx] = x; wx[nx] = w; wxs += w; ++nx;
        }
    }
    float acc = 0.f;
    for (int a = 0; a < ny; ++a) {
        float rowa = 0.f;
        for (int b2 = 0; b2 < nx; ++b2)
            rowa += wx[b2] * patch[(iy[a] * PHW + ix[b2]) * 3 + c];
        acc += wy[a] * rowa;
    }
    small[t] = acc / (wys * wxs);
}

// ---------------- kernel 2a: pure stream copy images -> out ----------------
__global__ void k_copy(const float4* __restrict__ in4, float4* __restrict__ out4) {
    int q = blockIdx.x * blockDim.x + threadIdx.x;
    out4[q] = in4[q];
}

// ---------------- kernel 2b: paste box pixels (highest covering box wins) ----------------
// grid: (row i = 0..127, box = 0..127), block: 128 threads (j)
__global__ void k_paste(const float* __restrict__ small, const int* __restrict__ box_yx,
                        const int* __restrict__ dec, float* __restrict__ out) {
    int box = blockIdx.y;              // flat b*NBOX+n
    int i   = blockIdx.x;              // row within box
    int j   = threadIdx.x;             // col within box
    int b   = box >> 4;
    int n   = box & (NBOX - 1);

    int by = box_yx[box * 2 + 0];
    int bx = box_yx[box * 2 + 1];
    int y  = by + i;
    int x  = bx + j;

    // skip if a LATER box of the same image covers this pixel (it owns the write)
    int base = (b << 4);
    for (int m = n + 1; m < NBOX; ++m) {
        int py = y - box_yx[(base + m) * 2 + 0];
        int px = x - box_yx[(base + m) * 2 + 1];
        if ((unsigned)py < (unsigned)PB && (unsigned)px < (unsigned)PB) return;
    }

    int d0 = dec[box * 3 + 0];
    int d1 = dec[box * 3 + 1];
    int d2 = dec[box * 3 + 2];
    int ii = i, jj = j;
    if (d2 > 0) ii = PB - 1 - ii;                    // undo flip_up_down
    if (d1 > 0) jj = PB - 1 - jj;                    // undo flip_left_right
    int si, sj;
    if (d0 > 0) { si = jj; sj = PB - 1 - ii; }       // undo rot90 k=1
    else        { si = ii; sj = jj; }

    const float* s = small + (si * PB + sj) * 3;
    float* o = out + ((size_t)b * (IMG_H * IMG_W) + (size_t)y * IMG_W + x) * 3;
    o[0] = s[0];
    o[1] = s[1];
    o[2] = s[2];
}

// ---------------- kernel 3: sum of inverse-transformed gathered grad tiles ----------------
__global__ void k_sgrad(const float* __restrict__ gradients, const int* __restrict__ box_yx,
                        const int* __restrict__ dec, float* __restrict__ s_part, int ngroups) {
    int g = blockIdx.y;
    int t = blockIdx.x * blockDim.x + threadIdx.x;      // 0 .. 49151
    if (t >= PB * PB * 3) return;
    int c    = t % 3;
    int rest = t / 3;
    int j    = rest % PB;
    int i    = rest / PB;
    int boxes_per = (NB * NBOX) / ngroups;
    float acc = 0.f;
    for (int m = 0; m < boxes_per; ++m) {
        int box = g * boxes_per + m;                    // flat index b*16+n (scan order)
        int b   = box >> 4;
        int by = box_yx[box * 2 + 0];
        int bx = box_yx[box * 2 + 1];
        int d0 = dec[box * 3 + 0];
        int d1 = dec[box * 3 + 1];
        int d2 = dec[box * 3 + 2];
        int ii = i, jj = j;
        if (d0 > 0) { int ti = PB - 1 - jj; int tj = ii; ii = ti; jj = tj; } // rot90 k=3 eval
        if (d1 > 0) jj = PB - 1 - jj;
        if (d2 > 0) ii = PB - 1 - ii;
        const float* gb = gradients + (size_t)b * (IMG_H * IMG_W * 3);
        acc += gb[((by + ii) * IMG_W + (bx + jj)) * 3 + c];
    }
    s_part[(size_t)g * (PB * PB * 3) + t] = acc;
}

// ---------------- kernel 4: upsample 128->256 (reducing partials) + TV gradient ----------------
__global__ void k_final(const float* __restrict__ s_part, const float* __restrict__ patch,
                        float* __restrict__ agg, int ngroups) {
    int t = blockIdx.x * blockDim.x + threadIdx.x;
    if (t >= PHW * PHW * 3) return;
    int c    = t % 3;
    int rest = t / 3;
    int v    = rest % PHW;
    int u    = rest / PHW;

    // ---- bilinear upsample taps ----
    float fy = 0.5f * u - 0.25f;
    float fx = 0.5f * v - 0.25f;
    int i0 = (int)floorf(fy);
    int j0 = (int)floorf(fx);
    float wy[2], wx[2];
    int   iy[2], jx[2];
    int ny = 0, nx = 0;
    float wys = 0.f, wxs = 0.f;
    #pragma unroll
    for (int d = 0; d < 2; ++d) {
        int i = i0 + d;
        if (i >= 0 && i < PB) {
            float w = 1.f - fabsf(fy - (float)i);
            iy[ny] = i; wy[ny] = w; wys += w; ++ny;
        }
        int jj = j0 + d;
        if (jj >= 0 && jj < PB) {
            float w = 1.f - fabsf(fx - (float)jj);
            jx[nx] = jj; wx[nx] = w; wxs += w; ++nx;
        }
    }
    float acc = 0.f;
    for (int a = 0; a < ny; ++a)
        for (int b2 = 0; b2 < nx; ++b2) {
            int idx = (iy[a] * PB + jx[b2]) * 3 + c;
            float sv = 0.f;
            for (int g = 0; g < ngroups; ++g)
                sv += s_part[(size_t)g * (PB * PB * 3) + idx];
            acc += wy[a] * wx[b2] * sv;
        }
    acc /= (wys * wxs);

    // ---- TV-loss gradient (closed form) ----
    #define PAT(a, b) patch[((a) * PHW + (b)) * 3 + c]
    float p  = PAT(u, v);
    float dx = (v < PHW - 1) ? (p - PAT(u, v + 1)) : 0.f;
    float dy = (u < PHW - 1) ? (p - PAT(u + 1, v)) : 0.f;
    float r  = sqrtf(dx * dx + dy * dy + EPSF);
    float gsum = (dx + dy) / r;
    if (v > 0) {
        float pl  = PAT(u, v - 1);
        float dxl = pl - p;
        float dyl = (u < PHW - 1) ? (pl - PAT(u + 1, v - 1)) : 0.f;
        gsum -= dxl / sqrtf(dxl * dxl + dyl * dyl + EPSF);
    }
    if (u > 0) {
        float pu_ = PAT(u - 1, v);
        float dyu = pu_ - p;
        float dxu = (v < PHW - 1) ? (pu_ - PAT(u - 1, v + 1)) : 0.f;
        gsum -= dyu / sqrtf(dxu * dxu + dyu * dyu + EPSF);
    }
    #undef PAT
    agg[t] = acc + 0.5f * gsum;
}

extern "C" void kernel_launch(void* const* d_in, const int* in_sizes, int n_in,
                              void* d_out, int out_size, void* d_ws, size_t ws_size,
                              hipStream_t stream) {
    const float* images    = (const float*)d_in[0];
    const float* gradients = (const float*)d_in[1];
    const float* patch     = (const float*)d_in[2];
    const int*   box_yx    = (const int*)d_in[3];
    const int*   dec       = (const int*)d_in[4];

    float* out     = (float*)d_out;
    float* agg_out = out + (size_t)NB * IMG_H * IMG_W * 3;

    const size_t TILE = PB * PB * 3;   // 49152 floats
    int ngroups = 16;
    if (ws_size < TILE * (size_t)(1 + 16) * sizeof(float)) ngroups = 8;
    if (ws_size < TILE * (size_t)(1 + 8)  * sizeof(float)) ngroups = 1;

    float* small  = (float*)d_ws;
    float* s_part = small + TILE;

    hipLaunchKernelGGL(k_downsample, dim3(192), dim3(256), 0, stream, patch, small);
    hipLaunchKernelGGL(k_sgrad, dim3(192, ngroups), dim3(256), 0, stream,
                       gradients, box_yx, dec, s_part, ngroups);
    hipLaunchKernelGGL(k_copy, dim3((IMG_H * IMG_W * 3 * NB) / 4 / 256), dim3(256), 0, stream,
                       (const float4*)images, (float4*)out);
    hipLaunchKernelGGL(k_paste, dim3(PB, NB * NBOX), dim3(PB), 0, stream,
                       small, box_yx, dec, out);
    hipLaunchKernelGGL(k_final, dim3((PHW * PHW * 3) / 256), dim3(256), 0, stream,
                       s_part, patch, agg_out, ngroups);
}

// Round 6
// 269.195 us; speedup vs baseline: 1.1088x; 1.0524x over previous
//
#include <hip/hip_runtime.h>
#include <math.h>

#define PB    128
#define PHW   256
#define IMG_H 1024
#define IMG_W 1024
#define NBOX  16
#define NB    8
#define EPSF  1e-12f

// ---------------- kernel 1: antialiased bilinear downsample 256 -> 128 ----------------
__global__ void k_downsample(const float* __restrict__ patch, float* __restrict__ small) {
    int t = blockIdx.x * blockDim.x + threadIdx.x;
    if (t >= PB * PB * 3) return;
    int c    = t % 3;
    int rest = t / 3;
    int jl   = rest % PB;
    int il   = rest / PB;
    float sy = 2.f * il + 0.5f;
    float sx = 2.f * jl + 0.5f;
    float wy[4], wx[4];
    int   iy[4], ix[4];
    int ny = 0, nx = 0;
    float wys = 0.f, wxs = 0.f;
    #pragma unroll
    for (int d = -1; d <= 2; ++d) {
        int y = 2 * il + d;
        if (y >= 0 && y < PHW) {
            float w = 1.f - 0.5f * fabsf(sy - (float)y);
            iy[ny] = y; wy[ny] = w; wys += w; ++ny;
        }
        int x = 2 * jl + d;
        if (x >= 0 && x < PHW) {
            float w = 1.f - 0.5f * fabsf(sx - (float)x);
            ix[nx] = x; wx[nx] = w; wxs += w; ++nx;
        }
    }
    float acc = 0.f;
    for (int a = 0; a < ny; ++a) {
        float rowa = 0.f;
        for (int b2 = 0; b2 < nx; ++b2)
            rowa += wx[b2] * patch[(iy[a] * PHW + ix[b2]) * 3 + c];
        acc += wy[a] * rowa;
    }
    small[t] = acc / (wys * wxs);
}

// ---------------- kernel 2a: pure stream copy images -> out ----------------
__global__ void k_copy(const float4* __restrict__ in4, float4* __restrict__ out4) {
    int q = blockIdx.x * blockDim.x + threadIdx.x;
    out4[q] = in4[q];
}

// ---------------- kernel 2b: paste box pixels (highest covering box wins) ----------------
__global__ void k_paste(const float* __restrict__ small, const int* __restrict__ box_yx,
                        const int* __restrict__ dec, float* __restrict__ out) {
    int box = blockIdx.y;              // flat b*NBOX+n
    int i   = blockIdx.x;              // row within box
    int j   = threadIdx.x;             // col within box
    int b   = box >> 4;
    int n   = box & (NBOX - 1);

    int by = box_yx[box * 2 + 0];
    int bx = box_yx[box * 2 + 1];
    int y  = by + i;
    int x  = bx + j;

    // skip if a LATER box of the same image covers this pixel (it owns the write)
    int base = (b << 4);
    for (int m = n + 1; m < NBOX; ++m) {
        int py = y - box_yx[(base + m) * 2 + 0];
        int px = x - box_yx[(base + m) * 2 + 1];
        if ((unsigned)py < (unsigned)PB && (unsigned)px < (unsigned)PB) return;
    }

    int d0 = dec[box * 3 + 0];
    int d1 = dec[box * 3 + 1];
    int d2 = dec[box * 3 + 2];
    int ii = i, jj = j;
    if (d2 > 0) ii = PB - 1 - ii;                    // undo flip_up_down
    if (d1 > 0) jj = PB - 1 - jj;                    // undo flip_left_right
    int si, sj;
    if (d0 > 0) { si = jj; sj = PB - 1 - ii; }       // undo rot90 k=1
    else        { si = ii; sj = jj; }

    const float* s = small + (si * PB + sj) * 3;
    float* o = out + ((size_t)b * (IMG_H * IMG_W) + (size_t)y * IMG_W + x) * 3;
    o[0] = s[0];
    o[1] = s[1];
    o[2] = s[2];
}

// ---------------- kernel 3: sum of inverse-transformed gathered grad tiles ----------------
template<int NG>
__global__ void k_sgrad(const float* __restrict__ gradients, const int* __restrict__ box_yx,
                        const int* __restrict__ dec, float* __restrict__ s_part) {
    int g = blockIdx.y;
    int t = blockIdx.x * blockDim.x + threadIdx.x;      // 0 .. 49151
    if (t >= PB * PB * 3) return;
    int c    = t % 3;
    int rest = t / 3;
    int j    = rest % PB;
    int i    = rest / PB;
    constexpr int BOXES_PER = (NB * NBOX) / NG;
    float acc = 0.f;
    #pragma unroll
    for (int m = 0; m < BOXES_PER; ++m) {
        int box = g * BOXES_PER + m;                    // flat index b*16+n (scan order)
        int b   = box >> 4;
        int by = box_yx[box * 2 + 0];
        int bx = box_yx[box * 2 + 1];
        int d0 = dec[box * 3 + 0];
        int d1 = dec[box * 3 + 1];
        int d2 = dec[box * 3 + 2];
        int ii = i, jj = j;
        if (d0 > 0) { int ti = PB - 1 - jj; int tj = ii; ii = ti; jj = tj; } // rot90 k=3 eval
        if (d1 > 0) jj = PB - 1 - jj;
        if (d2 > 0) ii = PB - 1 - ii;
        const float* gb = gradients + (size_t)b * (IMG_H * IMG_W * 3);
        acc += gb[((by + ii) * IMG_W + (bx + jj)) * 3 + c];
    }
    s_part[(size_t)g * (PB * PB * 3) + t] = acc;
}

// ---------------- kernel 4: reduce group partials ----------------
template<int NG>
__global__ void k_reduce(const float* __restrict__ s_part, float* __restrict__ S) {
    int t = blockIdx.x * blockDim.x + threadIdx.x;
    if (t >= PB * PB * 3) return;
    float a = 0.f;
    #pragma unroll
    for (int g = 0; g < NG; ++g) a += s_part[(size_t)g * (PB * PB * 3) + t];
    S[t] = a;
}

// ---------------- kernel 5: upsample 128->256 + TV-loss gradient ----------------
__global__ void k_final(const float* __restrict__ S, const float* __restrict__ patch,
                        float* __restrict__ agg) {
    int t = blockIdx.x * blockDim.x + threadIdx.x;
    if (t >= PHW * PHW * 3) return;
    int c    = t % 3;
    int rest = t / 3;
    int v    = rest % PHW;
    int u    = rest / PHW;

    float fy = 0.5f * u - 0.25f;
    float fx = 0.5f * v - 0.25f;
    int i0 = (int)floorf(fy);
    int j0 = (int)floorf(fx);
    float wy[2], wx[2];
    int   iy[2], jx[2];
    int ny = 0, nx = 0;
    float wys = 0.f, wxs = 0.f;
    #pragma unroll
    for (int d = 0; d < 2; ++d) {
        int i = i0 + d;
        if (i >= 0 && i < PB) {
            float w = 1.f - fabsf(fy - (float)i);
            iy[ny] = i; wy[ny] = w; wys += w; ++ny;
        }
        int jj = j0 + d;
        if (jj >= 0 && jj < PB) {
            float w = 1.f - fabsf(fx - (float)jj);
            jx[nx] = jj; wx[nx] = w; wxs += w; ++nx;
        }
    }
    float acc = 0.f;
    for (int a = 0; a < ny; ++a)
        for (int b2 = 0; b2 < nx; ++b2)
            acc += wy[a] * wx[b2] * S[(iy[a] * PB + jx[b2]) * 3 + c];
    acc /= (wys * wxs);

    // ---- TV-loss gradient (closed form) ----
    #define PAT(a, b) patch[((a) * PHW + (b)) * 3 + c]
    float p  = PAT(u, v);
    float dx = (v < PHW - 1) ? (p - PAT(u, v + 1)) : 0.f;
    float dy = (u < PHW - 1) ? (p - PAT(u + 1, v)) : 0.f;
    float r  = sqrtf(dx * dx + dy * dy + EPSF);
    float gsum = (dx + dy) / r;
    if (v > 0) {
        float pl  = PAT(u, v - 1);
        float dxl = pl - p;
        float dyl = (u < PHW - 1) ? (pl - PAT(u + 1, v - 1)) : 0.f;
        gsum -= dxl / sqrtf(dxl * dxl + dyl * dyl + EPSF);
    }
    if (u > 0) {
        float pu_ = PAT(u - 1, v);
        float dyu = pu_ - p;
        float dxu = (v < PHW - 1) ? (pu_ - PAT(u - 1, v + 1)) : 0.f;
        gsum -= dyu / sqrtf(dxu * dxu + dyu * dyu + EPSF);
    }
    #undef PAT
    agg[t] = acc + 0.5f * gsum;
}

extern "C" void kernel_launch(void* const* d_in, const int* in_sizes, int n_in,
                              void* d_out, int out_size, void* d_ws, size_t ws_size,
                              hipStream_t stream) {
    const float* images    = (const float*)d_in[0];
    const float* gradients = (const float*)d_in[1];
    const float* patch     = (const float*)d_in[2];
    const int*   box_yx    = (const int*)d_in[3];
    const int*   dec       = (const int*)d_in[4];

    float* out     = (float*)d_out;
    float* agg_out = out + (size_t)NB * IMG_H * IMG_W * 3;

    const size_t TILE = PB * PB * 3;   // 49152 floats
    bool big = ws_size >= TILE * (size_t)(1 + 16 + 1) * sizeof(float);
    int ngroups = big ? 16 : 1;

    float* small  = (float*)d_ws;
    float* s_part = small + TILE;
    float* S      = s_part + (size_t)ngroups * TILE;

    hipLaunchKernelGGL(k_downsample, dim3(192), dim3(256), 0, stream, patch, small);
    if (big) {
        hipLaunchKernelGGL((k_sgrad<16>), dim3(192, 16), dim3(256), 0, stream,
                           gradients, box_yx, dec, s_part);
        hipLaunchKernelGGL((k_reduce<16>), dim3(192), dim3(256), 0, stream, s_part, S);
    } else {
        hipLaunchKernelGGL((k_sgrad<1>), dim3(192, 1), dim3(256), 0, stream,
                           gradients, box_yx, dec, s_part);
        hipLaunchKernelGGL((k_reduce<1>), dim3(192), dim3(256), 0, stream, s_part, S);
    }
    hipLaunchKernelGGL(k_copy, dim3((IMG_H * IMG_W * 3 * NB) / 4 / 256), dim3(256), 0, stream,
                       (const float4*)images, (float4*)out);
    hipLaunchKernelGGL(k_paste, dim3(PB, NB * NBOX), dim3(PB), 0, stream,
                       small, box_yx, dec, out);
    hipLaunchKernelGGL(k_final, dim3((PHW * PHW * 3) / 256), dim3(256), 0, stream,
                       S, patch, agg_out);
}